// Round 15
// baseline (259.051 us; speedup 1.0000x reference)
//
#include <hip/hip_runtime.h>

typedef _Float16 h16;
typedef _Float16 h16x8 __attribute__((ext_vector_type(8)));
typedef float    f32x4 __attribute__((ext_vector_type(4)));

#define ELLW 40   // ELL width; P(deg>=40) ~ 3e-15 per node for Poisson(9)

// ---------- global->LDS direct (16B per lane, wave-uniform LDS base) ----------
__device__ __forceinline__ void gload16(const h16* g, h16* l) {
    __builtin_amdgcn_global_load_lds(
        (const __attribute__((address_space(1))) void*)g,
        (__attribute__((address_space(3))) void*)l,
        16, 0, 0);
}

// ---------- mega-prep: blocks [0,896) transpose 6 weight matrices; rest do flat work ----------
__global__ __launch_bounds__(256) void prep(
    const float* __restrict__ W0, const float* __restrict__ W1,
    const float* __restrict__ W2, const float* __restrict__ W3,
    const float* __restrict__ W4, const float* __restrict__ W5,
    h16* __restrict__ O0, h16* __restrict__ O1, h16* __restrict__ O2,
    h16* __restrict__ O3, h16* __restrict__ O4, h16* __restrict__ O5,
    const float* __restrict__ x, h16* __restrict__ xh,
    int* __restrict__ cursor,
    const int* __restrict__ batch, int* __restrict__ start,
    float* __restrict__ pooled, int Nn, int G)
{
    __shared__ float lds[32][33];
    const int b = blockIdx.x;
    if (b < 896) {   // ---- weight transpose tiles ----
        int mtx, t0;
        if      (b < 128) { mtx = 0; t0 = 0;   }
        else if (b < 256) { mtx = 1; t0 = 128; }
        else if (b < 512) { mtx = 2; t0 = 256; }
        else if (b < 768) { mtx = 3; t0 = 512; }
        else if (b < 832) { mtx = 4; t0 = 768; }
        else              { mtx = 5; t0 = 832; }
        const float* Ws[6] = {W0, W1, W2, W3, W4, W5};
        h16*         Os[6] = {O0, O1, O2, O3, O4, O5};
        const int    Ks[6] = {256, 256, 512, 512, 512, 512};
        const int    Ns[6] = {512, 512, 512, 512, 128, 128};
        const float* W = Ws[mtx];
        h16*         O = Os[mtx];
        const int K = Ks[mtx], N = Ns[mtx];
        const int tile = b - t0;
        const int tk = tile / (N >> 5), tn = tile % (N >> 5);
        const int t = threadIdx.x;
        const int r = t >> 3, c4 = (t & 7) * 4;
        float4 v = *(const float4*)(W + (size_t)(tk * 32 + r) * N + tn * 32 + c4);
        lds[r][c4] = v.x; lds[r][c4 + 1] = v.y; lds[r][c4 + 2] = v.z; lds[r][c4 + 3] = v.w;
        __syncthreads();
        h16* po = O + (size_t)(tn * 32 + r) * K + tk * 32 + c4;
        po[0] = (h16)lds[c4 + 0][r];
        po[1] = (h16)lds[c4 + 1][r];
        po[2] = (h16)lds[c4 + 2][r];
        po[3] = (h16)lds[c4 + 3][r];
        return;
    }
    // ---- flat work ----
    int i = (b - 896) * 256 + threadIdx.x;
    const int n_x = Nn * 32;                      // x cast, 8 elems each
    if (i < n_x) {
        float4 a = *(const float4*)(x + (size_t)i * 8);
        float4 c = *(const float4*)(x + (size_t)i * 8 + 4);
        h16x8 o = { (h16)a.x, (h16)a.y, (h16)a.z, (h16)a.w,
                    (h16)c.x, (h16)c.y, (h16)c.z, (h16)c.w };
        *(h16x8*)(xh + (size_t)i * 8) = o;
        return;
    }
    i -= n_x;
    if (i < Nn) { cursor[i] = 0; return; }
    i -= Nn;
    if (i < G * 128) { pooled[i] = 0.f; return; }
    i -= G * 128;
    if (i < Nn) {
        int bb = batch[i];
        int bp = (i == 0) ? -1 : batch[i - 1];
        for (int g = bp + 1; g <= bb; g++) start[g] = i;
        if (i == Nn - 1) for (int g = bb + 1; g <= G; g++) start[g] = Nn;
    }
}

// ---------- ELL scatter (dst-grouped adjacency; cursor becomes degree) ----------
__global__ void scatter_ell(const int* __restrict__ ei, int E, int Nn,
                            int* __restrict__ cursor, int* __restrict__ ssrc) {
    int i = blockIdx.x * blockDim.x + threadIdx.x;
    if (i >= E + Nn) return;
    int src, dst;
    if (i < E) { src = ei[i]; dst = ei[E + i]; }
    else       { src = dst = i - E; }
    int p = atomicAdd(&cursor[dst], 1);
    if (p < ELLW) ssrc[dst * ELLW + p] = src;
}

// ---------- XCD-aware tile remap (grid total % 8 == 0) ----------
__device__ __forceinline__ void xcd_tiles(int& mt, int& nt) {
    int d = blockIdx.x + blockIdx.y * gridDim.x;
    int k = d & 7, j = d >> 3;
    mt = k * (gridDim.y >> 3) + j / gridDim.x;
    nt = j % gridDim.x;
}

// ---------- wide f16 MFMA GEMM: 128x256 tile, 8 waves, BK=64, SINGLE-buffered ----------
// 48 KB LDS -> 3 blocks/CU co-resident: cross-block wave overlap hides the
// barrier vmcnt-drain (m97/m114 regime).
__global__ __launch_bounds__(512) void gemm_f16_wide(
    const h16* __restrict__ Xh, const h16* __restrict__ Wt,
    const float* __restrict__ bias_lo, const float* __restrict__ bias_hi, int nsplit,
    h16* __restrict__ Yl, h16* __restrict__ Yr, int M, int N, int K)
{
    __shared__ __align__(16) h16 As[128 * 64];   // 16 KB
    __shared__ __align__(16) h16 Bs[256 * 64];   // 32 KB

    int mt, nt;
    xcd_tiles(mt, nt);
    const int m0 = mt * 128;
    const int n0 = nt * 256;
    const int t = threadIdx.x;
    const int lane = t & 63;
    const int wid = t >> 6;
    const int wr = wid >> 2;
    const int wc = wid & 3;

    f32x4 acc[4][4] = {};

    const int lr = lane >> 3;
    const int sl = lane & 7;

    const int nkb = K >> 6;
    for (int kb = 0; kb < nkb; kb++) {
        const int k0 = kb << 6;
        #pragma unroll
        for (int q = 0; q < 6; q++) {
            int rb = wid + 8 * q;                 // 8-row block id, 0..47
            if (rb < 16) {
                int r = rb * 8 + lr;
                int col = (sl ^ (r & 7)) << 3;
                gload16(Xh + (size_t)(m0 + r) * K + k0 + col, &As[rb * 8 * 64]);
            } else {
                int c = (rb - 16) * 8 + lr;
                int col = (sl ^ (c & 7)) << 3;
                gload16(Wt + (size_t)(n0 + c) * K + k0 + col, &Bs[(rb - 16) * 8 * 64]);
            }
        }
        __syncthreads();
        #pragma unroll
        for (int ks = 0; ks < 2; ks++) {
            h16x8 af[4], bf[4];
            #pragma unroll
            for (int i = 0; i < 4; i++) {
                int r  = wr * 64 + i * 16 + (lane & 15);
                int s2 = ks * 4 + (lane >> 4);
                af[i] = *(const h16x8*)(&As[r * 64 + ((s2 ^ (r & 7)) << 3)]);
                int c  = wc * 64 + i * 16 + (lane & 15);
                bf[i] = *(const h16x8*)(&Bs[c * 64 + ((s2 ^ (c & 7)) << 3)]);
            }
            #pragma unroll
            for (int i = 0; i < 4; i++)
                #pragma unroll
                for (int j = 0; j < 4; j++)
                    acc[i][j] = __builtin_amdgcn_mfma_f32_16x16x32_f16(af[i], bf[j], acc[i][j], 0, 0, 0);
        }
        __syncthreads();
    }

    const int crow = (lane >> 4) * 4;
    const int ccol = lane & 15;
    #pragma unroll
    for (int i = 0; i < 4; i++) {
        int rg = m0 + wr * 64 + i * 16 + crow;
        #pragma unroll
        for (int j = 0; j < 4; j++) {
            int cg = n0 + wc * 64 + j * 16 + ccol;
            float b = (cg < nsplit) ? bias_lo[cg] : bias_hi[cg - nsplit];
            h16* dst = (cg < nsplit) ? (Yl + (size_t)cg) : (Yr + (size_t)(cg - nsplit));
            #pragma unroll
            for (int rr = 0; rr < 4; rr++)
                dst[(size_t)(rg + rr) * nsplit] = (h16)(acc[i][j][rr] + b);
        }
    }
}

// ---------- narrow f16 MFMA GEMM (layer 3): 128x128 tile, 4 waves, dbuf ----------
// grid = 256 blocks = 1/CU (grid-limited) -> keep per-block prefetch.
__global__ __launch_bounds__(256) void gemm_f16_mfma(
    const h16* __restrict__ Xh, const h16* __restrict__ Wt,
    const float* __restrict__ bias_lo, const float* __restrict__ bias_hi, int nsplit,
    h16* __restrict__ Yl, h16* __restrict__ Yr, int M, int N, int K)
{
    __shared__ __align__(16) h16 As[2][128 * 64];
    __shared__ __align__(16) h16 Bs[2][128 * 64];

    int mt, nt;
    xcd_tiles(mt, nt);
    const int m0 = mt * 128;
    const int n0 = nt * 128;
    const int t = threadIdx.x;
    const int lane = t & 63;
    const int wid = t >> 6;
    const int wr = wid >> 1, wc = wid & 1;

    f32x4 acc[4][4] = {};

    const int rA = wid * 32;
    const int lr = lane >> 3;
    const int sl = lane & 7;

    #define STAGE(b, k0)                                                        \
        _Pragma("unroll")                                                       \
        for (int q = 0; q < 4; q++) {                                           \
            int rb = rA + q * 8;                                                \
            int r  = rb + lr;                                                   \
            int col = (sl ^ (r & 7)) << 3;                                      \
            gload16(Xh + (size_t)(m0 + r) * K + (k0) + col, &As[b][rb * 64]);   \
            gload16(Wt + (size_t)(n0 + r) * K + (k0) + col, &Bs[b][rb * 64]);   \
        }

    STAGE(0, 0)
    __syncthreads();

    const int nkb = K >> 6;
    int buf = 0;
    for (int kb = 0; kb < nkb; kb++) {
        if (kb + 1 < nkb) { STAGE(buf ^ 1, (kb + 1) << 6) }
        #pragma unroll
        for (int ks = 0; ks < 2; ks++) {
            h16x8 af[4], bf[4];
            #pragma unroll
            for (int i = 0; i < 4; i++) {
                int r  = wr * 64 + i * 16 + (lane & 15);
                int s2 = ks * 4 + (lane >> 4);
                af[i] = *(const h16x8*)(&As[buf][r * 64 + ((s2 ^ (r & 7)) << 3)]);
                int c  = wc * 64 + i * 16 + (lane & 15);
                bf[i] = *(const h16x8*)(&Bs[buf][c * 64 + ((s2 ^ (c & 7)) << 3)]);
            }
            #pragma unroll
            for (int i = 0; i < 4; i++)
                #pragma unroll
                for (int j = 0; j < 4; j++)
                    acc[i][j] = __builtin_amdgcn_mfma_f32_16x16x32_f16(af[i], bf[j], acc[i][j], 0, 0, 0);
        }
        __syncthreads();
        buf ^= 1;
    }
    #undef STAGE

    const int crow = (lane >> 4) * 4;
    const int ccol = lane & 15;
    #pragma unroll
    for (int i = 0; i < 4; i++) {
        int rg = m0 + wr * 64 + i * 16 + crow;
        #pragma unroll
        for (int j = 0; j < 4; j++) {
            int cg = n0 + wc * 64 + j * 16 + ccol;
            float b = (cg < nsplit) ? bias_lo[cg] : bias_hi[cg - nsplit];
            h16* dst = (cg < nsplit) ? (Yl + (size_t)cg) : (Yr + (size_t)(cg - nsplit));
            #pragma unroll
            for (int rr = 0; rr < 4; rr++)
                dst[(size_t)(rg + rr) * nsplit] = (h16)(acc[i][j][rr] + b);
        }
    }
}

// ---------- fused per-node GATv2 attention, D=512 ----------
// wave per node; guarded 16-slot gather batch (P(deg<=16)~98.8%): ONE latency
// exposure for nearly all nodes. Invalid slots: xv=0, score=-inf -> p=0 exactly.
// Validity is prefix-monotone so m is finite before any invalid update.
template<int H, int C>
__global__ __launch_bounds__(256) void node_attn(
    const h16* __restrict__ xl, const h16* __restrict__ xr,
    const float* __restrict__ att, const float* __restrict__ bias,
    const int* __restrict__ deg, const int* __restrict__ ssrc,
    h16* __restrict__ out, int Nn)
{
    constexpr int D   = H * C;
    constexpr int EPL = D / 64;     // 8
    constexpr int LPH = C / EPL;    // 16
    int node = blockIdx.x * (blockDim.x >> 6) + (threadIdx.x >> 6);
    if (node >= Nn) return;
    const int lane = threadIdx.x & 63;
    const int base = lane * EPL;

    float xrv[EPL], attv[EPL];
    {
        h16x8 v = *(const h16x8*)(xr + (size_t)node * D + base);
        float4 a0 = *(const float4*)(att + base);
        float4 a1 = *(const float4*)(att + base + 4);
        #pragma unroll
        for (int j = 0; j < 8; j++) xrv[j] = (float)v[j];
        attv[0] = a0.x; attv[1] = a0.y; attv[2] = a0.z; attv[3] = a0.w;
        attv[4] = a1.x; attv[5] = a1.y; attv[6] = a1.z; attv[7] = a1.w;
    }

    float m = -INFINITY, denom = 0.f;
    float agg[EPL] = {};

    auto score8 = [&](h16x8 v) {
        float s = 0.f;
        #pragma unroll
        for (int j = 0; j < 8; j++) {
            float u = (float)v[j] + xrv[j];
            u = u > 0.f ? u : 0.2f * u;
            s += u * attv[j];
        }
        return s;
    };
    auto update8 = [&](float s, h16x8 v) {
        if (s > m) {
            float scale = __expf(m - s);
            denom *= scale;
            #pragma unroll
            for (int j = 0; j < 8; j++) agg[j] *= scale;
            m = s;
        }
        float p = __expf(s - m);
        denom += p;
        #pragma unroll
        for (int j = 0; j < 8; j++) agg[j] += p * (float)v[j];
    };

    const int e0  = node * ELLW;
    const int dgn = deg[node];

    {   // guarded 16-slot batch: all gathers issued before any use
        h16x8 xv[16];
        float sc[16];
        const int nf = dgn < 16 ? dgn : 16;
        #pragma unroll
        for (int g = 0; g < 16; g++) {
            if (g < nf) {
                int s = ssrc[e0 + g];
                xv[g] = *(const h16x8*)(xl + (size_t)s * D + base);
            } else {
                #pragma unroll
                for (int j = 0; j < 8; j++) xv[g][j] = (h16)0.f;
            }
        }
        #pragma unroll
        for (int g = 0; g < 16; g++) sc[g] = (g < nf) ? score8(xv[g]) : -INFINITY;
        #pragma unroll
        for (int o = 1; o < LPH; o <<= 1)
            #pragma unroll
            for (int g = 0; g < 16; g++) sc[g] += __shfl_xor(sc[g], o, 64);
        #pragma unroll
        for (int g = 0; g < 16; g++) update8(sc[g], xv[g]);
    }
    // rare tail (deg > 16, P ~ 1.2%)
    for (int e = e0 + 16; e < e0 + dgn; e++) {
        int s0 = ssrc[e];
        h16x8 xa = *(const h16x8*)(xl + (size_t)s0 * D + base);
        float sc0 = score8(xa);
        #pragma unroll
        for (int o = 1; o < LPH; o <<= 1) sc0 += __shfl_xor(sc0, o, 64);
        update8(sc0, xa);
    }

    h16* po = out + (size_t)node * D + base;
    h16x8 o8;
    #pragma unroll
    for (int j = 0; j < 8; j++) {
        float v = agg[j] / denom + bias[base + j];
        o8[j] = (h16)(v > 0.f ? v : 0.01f * v);
    }
    *(h16x8*)po = o8;
}

// ---------- layer-3 attention, H=1 D=128: 16 lanes/edge, 4 edge-streams/wave ----------
// guarded 4-slot batch per quarter (covers deg<=16); outputs h16.
// Empty-quarter pollution is nullified in the merge by exp(m_bad - mn) = 0.
__global__ __launch_bounds__(256) void node_attn_h1(
    const h16* __restrict__ xl, const h16* __restrict__ xr,
    const float* __restrict__ att, const float* __restrict__ bias,
    const int* __restrict__ deg, const int* __restrict__ ssrc,
    h16* __restrict__ out, int Nn)
{
    int node = blockIdx.x * 4 + (threadIdx.x >> 6);
    if (node >= Nn) return;
    const int lane = threadIdx.x & 63;
    const int q    = lane >> 4;
    const int sl   = lane & 15;
    const int base = sl * 8;

    float xrv[8], attv[8];
    {
        h16x8 v = *(const h16x8*)(xr + (size_t)node * 128 + base);
        float4 a0 = *(const float4*)(att + base);
        float4 a1 = *(const float4*)(att + base + 4);
        #pragma unroll
        for (int j = 0; j < 8; j++) xrv[j] = (float)v[j];
        attv[0] = a0.x; attv[1] = a0.y; attv[2] = a0.z; attv[3] = a0.w;
        attv[4] = a1.x; attv[5] = a1.y; attv[6] = a1.z; attv[7] = a1.w;
    }

    float m = -1e30f, denom = 0.f;
    float agg[8] = {};

    const int e0  = node * ELLW;
    const int dgn = deg[node];
    const int e1  = e0 + dgn;

    auto upd = [&](float s, h16x8 v) {
        if (s > m) {
            float sc = __expf(m - s);
            denom *= sc;
            #pragma unroll
            for (int j = 0; j < 8; j++) agg[j] *= sc;
            m = s;
        }
        float p = __expf(s - m);
        denom += p;
        #pragma unroll
        for (int j = 0; j < 8; j++) agg[j] += p * (float)v[j];
    };
    auto sc8 = [&](h16x8 v) {
        float s = 0.f;
        #pragma unroll
        for (int j = 0; j < 8; j++) {
            float u = (float)v[j] + xrv[j];
            u = u > 0.f ? u : 0.2f * u;
            s += u * attv[j];
        }
        return s;
    };

    {   // guarded 4-slot batch (this quarter's first 4 edges: e0+q+4g)
        h16x8 xv[4];
        float sc[4];
        #pragma unroll
        for (int g = 0; g < 4; g++) {
            int e = e0 + q + g * 4;
            if (e < e1) {
                int src = ssrc[e];
                xv[g] = *(const h16x8*)(xl + (size_t)src * 128 + base);
            } else {
                #pragma unroll
                for (int j = 0; j < 8; j++) xv[g][j] = (h16)0.f;
            }
        }
        #pragma unroll
        for (int g = 0; g < 4; g++) {
            int e = e0 + q + g * 4;
            sc[g] = (e < e1) ? sc8(xv[g]) : -1e30f;
        }
        #pragma unroll
        for (int o = 1; o < 16; o <<= 1)
            #pragma unroll
            for (int g = 0; g < 4; g++) sc[g] += __shfl_xor(sc[g], o, 64);
        #pragma unroll
        for (int g = 0; g < 4; g++) upd(sc[g], xv[g]);
    }
    // rare tail (deg > 16)
    for (int e = e0 + q + 16; e < e1; e += 4) {
        int src = ssrc[e];
        h16x8 v = *(const h16x8*)(xl + (size_t)src * 128 + base);
        float s = sc8(v);
        #pragma unroll
        for (int o = 1; o < 16; o <<= 1) s += __shfl_xor(s, o, 64);
        upd(s, v);
    }

    #pragma unroll
    for (int o = 16; o <= 32; o <<= 1) {
        float m2 = __shfl_xor(m, o, 64);
        float d2 = __shfl_xor(denom, o, 64);
        float a2[8];
        #pragma unroll
        for (int j = 0; j < 8; j++) a2[j] = __shfl_xor(agg[j], o, 64);
        float mn = fmaxf(m, m2);
        float sa = __expf(m - mn), sb = __expf(m2 - mn);
        denom = denom * sa + d2 * sb;
        #pragma unroll
        for (int j = 0; j < 8; j++) agg[j] = agg[j] * sa + a2[j] * sb;
        m = mn;
    }

    if (lane < 16) {
        h16* po = out + (size_t)node * 128 + base;
        h16x8 o8;
        #pragma unroll
        for (int j = 0; j < 8; j++) {
            float v = agg[j] / denom + bias[base + j];
            o8[j] = (h16)(v > 0.f ? v : 0.01f * v);
        }
        *(h16x8*)po = o8;
    }
}

// ---------- pooling: 256 blocks, slab-parallel, flush on graph change ----------
__global__ __launch_bounds__(128) void pool_partial(
    const h16* __restrict__ h, const int* __restrict__ batch,
    float* __restrict__ pooled, int Nn, int spb)
{
    int t = threadIdx.x;
    int n0 = blockIdx.x * spb;
    int n1 = min(n0 + spb, Nn);
    if (n0 >= n1) return;
    int cur = batch[n0];
    float acc = 0.f;
    for (int n = n0; n < n1; n++) {
        int g = batch[n];
        if (g != cur) {
            atomicAdd(&pooled[cur * 128 + t], acc);
            acc = 0.f; cur = g;
        }
        acc += (float)h[(size_t)n * 128 + t];
    }
    atomicAdd(&pooled[cur * 128 + t], acc);
}

// ---------- classifier ----------
__global__ __launch_bounds__(128) void classifier(
    const float* __restrict__ pooled, const int* __restrict__ start,
    const float* __restrict__ gf,
    const float* __restrict__ W1, const float* __restrict__ b1,
    const float* __restrict__ W2, const float* __restrict__ b2,
    float* __restrict__ out)
{
    __shared__ float z[130];
    __shared__ float hid[128];
    int g = blockIdx.x, t = threadIdx.x;
    float cnt = fmaxf((float)(start[g + 1] - start[g]), 1.f);
    z[t] = pooled[g * 128 + t] / cnt;
    if (t < 2) z[128 + t] = gf[g * 2 + t];
    __syncthreads();
    float s = b1[t];
    for (int k = 0; k < 130; k++) s += z[k] * W1[k * 128 + t];
    hid[t] = s > 0.f ? s : 0.01f * s;
    __syncthreads();
    if (t < 2) {
        float o = b2[t];
        for (int j = 0; j < 128; j++) o += hid[j] * W2[j * 2 + t];
        out[g * 2 + t] = o;
    }
}

// ---------- host ----------
static inline int cdiv(int a, int b) { return (a + b - 1) / b; }

extern "C" void kernel_launch(void* const* d_in, const int* in_sizes, int n_in,
                              void* d_out, int out_size, void* d_ws, size_t ws_size,
                              hipStream_t stream)
{
    const float* x     = (const float*)d_in[0];
    const int*   ei    = (const int*)d_in[1];
    const int*   batch = (const int*)d_in[2];
    const float* gf    = (const float*)d_in[3];

    const float* c_Wl[3]   = {(const float*)d_in[4],  (const float*)d_in[10], (const float*)d_in[16]};
    const float* c_bl[3]   = {(const float*)d_in[5],  (const float*)d_in[11], (const float*)d_in[17]};
    const float* c_Wr[3]   = {(const float*)d_in[6],  (const float*)d_in[12], (const float*)d_in[18]};
    const float* c_br[3]   = {(const float*)d_in[7],  (const float*)d_in[13], (const float*)d_in[19]};
    const float* c_att[3]  = {(const float*)d_in[8],  (const float*)d_in[14], (const float*)d_in[20]};
    const float* c_bias[3] = {(const float*)d_in[9],  (const float*)d_in[15], (const float*)d_in[21]};
    const float* W1 = (const float*)d_in[22];
    const float* b1 = (const float*)d_in[23];
    const float* W2 = (const float*)d_in[24];
    const float* b2 = (const float*)d_in[25];
    float* out = (float*)d_out;

    const int Nn   = in_sizes[0] / 256;   // 16384
    const int E    = in_sizes[1] / 2;     // 131072
    const int G    = in_sizes[3] / 2;     // 64
    const int Etot = E + Nn;

    char* w = (char*)d_ws;
    auto carve = [&](size_t bytes) { void* p = w; w += (bytes + 255) & ~(size_t)255; return p; };
    h16*   ylb  = (h16*)carve((size_t)Nn * 512 * 2);    // xl buffer
    h16*   yrb  = (h16*)carve((size_t)Nn * 512 * 2);    // xr buffer
    h16*   xh   = (h16*)carve((size_t)Nn * 512 * 2);    // f16 activations
    h16*   b0   = (h16*)carve((size_t)Nn * 128 * 2);    // layer-3 output (f16)
    h16* wt1 = (h16*)carve((size_t)1024 * 256 * 2);     // [Wl1^T ; Wr1^T]
    h16* wt2 = (h16*)carve((size_t)1024 * 512 * 2);     // [Wl2^T ; Wr2^T]
    h16* wt3 = (h16*)carve((size_t)256 * 512 * 2);      // [Wl3^T ; Wr3^T]
    int* cursor = (int*)carve((size_t)Nn * 4);          // becomes deg after scatter
    int* ssrc   = (int*)carve((size_t)Nn * ELLW * 4);   // ELL adjacency
    int* start  = (int*)carve((size_t)(G + 1) * 4);
    float* pooled = (float*)carve((size_t)G * 128 * 4);
    (void)ws_size; (void)n_in; (void)out_size;

    // ---- mega-prep: weight transpose (896 blocks) + flat work ----
    {
        const int flat = Nn * 32 + Nn + G * 128 + Nn;
        prep<<<896 + cdiv(flat, 256), 256, 0, stream>>>(
            c_Wl[0], c_Wr[0], c_Wl[1], c_Wr[1], c_Wl[2], c_Wr[2],
            wt1, wt1 + 512 * 256, wt2, wt2 + 512 * 512, wt3, wt3 + 128 * 512,
            x, xh, cursor, batch, start, pooled, Nn, G);
    }
    // ---- ELL adjacency (dst-grouped) ----
    scatter_ell<<<cdiv(Etot, 256), 256, 0, stream>>>(ei, E, Nn, cursor, ssrc);

    const int node_blocks = cdiv(Nn, 4);

    // ---- layer 1: xh [N,256] -> xl|xr [N,512] each ----
    gemm_f16_wide<<<dim3(1024 / 256, Nn / 128), 512, 0, stream>>>(xh, wt1, c_bl[0], c_br[0], 512, ylb, yrb, Nn, 1024, 256);
    node_attn<4, 128><<<node_blocks, 256, 0, stream>>>(ylb, yrb, c_att[0], c_bias[0], cursor, ssrc, xh, Nn);
    // ---- layer 2 ----
    gemm_f16_wide<<<dim3(1024 / 256, Nn / 128), 512, 0, stream>>>(xh, wt2, c_bl[1], c_br[1], 512, ylb, yrb, Nn, 1024, 512);
    node_attn<4, 128><<<node_blocks, 256, 0, stream>>>(ylb, yrb, c_att[1], c_bias[1], cursor, ssrc, xh, Nn);
    // ---- layer 3: xh [N,512] -> xl|xr [N,128] each (H=1) ----
    gemm_f16_mfma<<<dim3(256 / 128, Nn / 128), 256, 0, stream>>>(xh, wt3, c_bl[2], c_br[2], 128, ylb, yrb, Nn, 256, 512);
    node_attn_h1<<<node_blocks, 256, 0, stream>>>(ylb, yrb, c_att[2], c_bias[2], cursor, ssrc, b0, Nn);

    // ---- global mean pool (slab-parallel) + classifier ----
    {
        const int nblk = 256;
        const int spb  = cdiv(Nn, nblk);
        pool_partial<<<nblk, 128, 0, stream>>>(b0, batch, pooled, Nn, spb);
    }
    classifier<<<G, 128, 0, stream>>>(pooled, start, gf, W1, b1, W2, b2, out);
}

// Round 16
// 184.500 us; speedup vs baseline: 1.4041x; 1.4041x over previous
//
#include <hip/hip_runtime.h>

typedef _Float16 h16;
typedef _Float16 h16x8 __attribute__((ext_vector_type(8)));
typedef float    f32x4 __attribute__((ext_vector_type(4)));

#define ELLW 40   // ELL width; P(deg>=40) ~ 3e-15 per node for Poisson(9)

// ---------- global->LDS direct (16B per lane, wave-uniform LDS base) ----------
__device__ __forceinline__ void gload16(const h16* g, h16* l) {
    __builtin_amdgcn_global_load_lds(
        (const __attribute__((address_space(1))) void*)g,
        (__attribute__((address_space(3))) void*)l,
        16, 0, 0);
}

// ---------- mega-prep: blocks [0,896) transpose 6 weight matrices; rest do flat work ----------
__global__ __launch_bounds__(256) void prep(
    const float* __restrict__ W0, const float* __restrict__ W1,
    const float* __restrict__ W2, const float* __restrict__ W3,
    const float* __restrict__ W4, const float* __restrict__ W5,
    h16* __restrict__ O0, h16* __restrict__ O1, h16* __restrict__ O2,
    h16* __restrict__ O3, h16* __restrict__ O4, h16* __restrict__ O5,
    const float* __restrict__ x, h16* __restrict__ xh,
    int* __restrict__ cursor,
    const int* __restrict__ batch, int* __restrict__ start,
    float* __restrict__ pooled, int Nn, int G)
{
    __shared__ float lds[32][33];
    const int b = blockIdx.x;
    if (b < 896) {   // ---- weight transpose tiles ----
        int mtx, t0;
        if      (b < 128) { mtx = 0; t0 = 0;   }
        else if (b < 256) { mtx = 1; t0 = 128; }
        else if (b < 512) { mtx = 2; t0 = 256; }
        else if (b < 768) { mtx = 3; t0 = 512; }
        else if (b < 832) { mtx = 4; t0 = 768; }
        else              { mtx = 5; t0 = 832; }
        const float* Ws[6] = {W0, W1, W2, W3, W4, W5};
        h16*         Os[6] = {O0, O1, O2, O3, O4, O5};
        const int    Ks[6] = {256, 256, 512, 512, 512, 512};
        const int    Ns[6] = {512, 512, 512, 512, 128, 128};
        const float* W = Ws[mtx];
        h16*         O = Os[mtx];
        const int K = Ks[mtx], N = Ns[mtx];
        const int tile = b - t0;
        const int tk = tile / (N >> 5), tn = tile % (N >> 5);
        const int t = threadIdx.x;
        const int r = t >> 3, c4 = (t & 7) * 4;
        float4 v = *(const float4*)(W + (size_t)(tk * 32 + r) * N + tn * 32 + c4);
        lds[r][c4] = v.x; lds[r][c4 + 1] = v.y; lds[r][c4 + 2] = v.z; lds[r][c4 + 3] = v.w;
        __syncthreads();
        h16* po = O + (size_t)(tn * 32 + r) * K + tk * 32 + c4;
        po[0] = (h16)lds[c4 + 0][r];
        po[1] = (h16)lds[c4 + 1][r];
        po[2] = (h16)lds[c4 + 2][r];
        po[3] = (h16)lds[c4 + 3][r];
        return;
    }
    // ---- flat work ----
    int i = (b - 896) * 256 + threadIdx.x;
    const int n_x = Nn * 32;                      // x cast, 8 elems each
    if (i < n_x) {
        float4 a = *(const float4*)(x + (size_t)i * 8);
        float4 c = *(const float4*)(x + (size_t)i * 8 + 4);
        h16x8 o = { (h16)a.x, (h16)a.y, (h16)a.z, (h16)a.w,
                    (h16)c.x, (h16)c.y, (h16)c.z, (h16)c.w };
        *(h16x8*)(xh + (size_t)i * 8) = o;
        return;
    }
    i -= n_x;
    if (i < Nn) { cursor[i] = 0; return; }
    i -= Nn;
    if (i < G * 128) { pooled[i] = 0.f; return; }
    i -= G * 128;
    if (i < Nn) {
        int bb = batch[i];
        int bp = (i == 0) ? -1 : batch[i - 1];
        for (int g = bp + 1; g <= bb; g++) start[g] = i;
        if (i == Nn - 1) for (int g = bb + 1; g <= G; g++) start[g] = Nn;
    }
}

// ---------- ELL scatter (dst-grouped adjacency; cursor becomes degree) ----------
__global__ void scatter_ell(const int* __restrict__ ei, int E, int Nn,
                            int* __restrict__ cursor, int* __restrict__ ssrc) {
    int i = blockIdx.x * blockDim.x + threadIdx.x;
    if (i >= E + Nn) return;
    int src, dst;
    if (i < E) { src = ei[i]; dst = ei[E + i]; }
    else       { src = dst = i - E; }
    int p = atomicAdd(&cursor[dst], 1);
    if (p < ELLW) ssrc[dst * ELLW + p] = src;
}

// ---------- XCD-aware tile remap (grid total % 8 == 0) ----------
__device__ __forceinline__ void xcd_tiles(int& mt, int& nt) {
    int d = blockIdx.x + blockIdx.y * gridDim.x;
    int k = d & 7, j = d >> 3;
    mt = k * (gridDim.y >> 3) + j / gridDim.x;
    nt = j % gridDim.x;
}

// ---------- wide f16 MFMA GEMM: 128x256 tile, 8 waves, BK=64, SINGLE-buffered ----------
// 48 KB LDS -> 3 blocks/CU co-resident: cross-block wave overlap hides the
// barrier vmcnt-drain (m97/m114 regime).
__global__ __launch_bounds__(512) void gemm_f16_wide(
    const h16* __restrict__ Xh, const h16* __restrict__ Wt,
    const float* __restrict__ bias_lo, const float* __restrict__ bias_hi, int nsplit,
    h16* __restrict__ Yl, h16* __restrict__ Yr, int M, int N, int K)
{
    __shared__ __align__(16) h16 As[128 * 64];   // 16 KB
    __shared__ __align__(16) h16 Bs[256 * 64];   // 32 KB

    int mt, nt;
    xcd_tiles(mt, nt);
    const int m0 = mt * 128;
    const int n0 = nt * 256;
    const int t = threadIdx.x;
    const int lane = t & 63;
    const int wid = t >> 6;
    const int wr = wid >> 2;
    const int wc = wid & 3;

    f32x4 acc[4][4] = {};

    const int lr = lane >> 3;
    const int sl = lane & 7;

    const int nkb = K >> 6;
    for (int kb = 0; kb < nkb; kb++) {
        const int k0 = kb << 6;
        #pragma unroll
        for (int q = 0; q < 6; q++) {
            int rb = wid + 8 * q;                 // 8-row block id, 0..47
            if (rb < 16) {
                int r = rb * 8 + lr;
                int col = (sl ^ (r & 7)) << 3;
                gload16(Xh + (size_t)(m0 + r) * K + k0 + col, &As[rb * 8 * 64]);
            } else {
                int c = (rb - 16) * 8 + lr;
                int col = (sl ^ (c & 7)) << 3;
                gload16(Wt + (size_t)(n0 + c) * K + k0 + col, &Bs[(rb - 16) * 8 * 64]);
            }
        }
        __syncthreads();
        #pragma unroll
        for (int ks = 0; ks < 2; ks++) {
            h16x8 af[4], bf[4];
            #pragma unroll
            for (int i = 0; i < 4; i++) {
                int r  = wr * 64 + i * 16 + (lane & 15);
                int s2 = ks * 4 + (lane >> 4);
                af[i] = *(const h16x8*)(&As[r * 64 + ((s2 ^ (r & 7)) << 3)]);
                int c  = wc * 64 + i * 16 + (lane & 15);
                bf[i] = *(const h16x8*)(&Bs[c * 64 + ((s2 ^ (c & 7)) << 3)]);
            }
            #pragma unroll
            for (int i = 0; i < 4; i++)
                #pragma unroll
                for (int j = 0; j < 4; j++)
                    acc[i][j] = __builtin_amdgcn_mfma_f32_16x16x32_f16(af[i], bf[j], acc[i][j], 0, 0, 0);
        }
        __syncthreads();
    }

    const int crow = (lane >> 4) * 4;
    const int ccol = lane & 15;
    #pragma unroll
    for (int i = 0; i < 4; i++) {
        int rg = m0 + wr * 64 + i * 16 + crow;
        #pragma unroll
        for (int j = 0; j < 4; j++) {
            int cg = n0 + wc * 64 + j * 16 + ccol;
            float b = (cg < nsplit) ? bias_lo[cg] : bias_hi[cg - nsplit];
            h16* dst = (cg < nsplit) ? (Yl + (size_t)cg) : (Yr + (size_t)(cg - nsplit));
            #pragma unroll
            for (int rr = 0; rr < 4; rr++)
                dst[(size_t)(rg + rr) * nsplit] = (h16)(acc[i][j][rr] + b);
        }
    }
}

// ---------- narrow f16 MFMA GEMM (layer 3): 128x128 tile, 4 waves, dbuf ----------
// grid = 256 blocks = 1/CU (grid-limited) -> keep per-block prefetch.
__global__ __launch_bounds__(256) void gemm_f16_mfma(
    const h16* __restrict__ Xh, const h16* __restrict__ Wt,
    const float* __restrict__ bias_lo, const float* __restrict__ bias_hi, int nsplit,
    h16* __restrict__ Yl, h16* __restrict__ Yr, int M, int N, int K)
{
    __shared__ __align__(16) h16 As[2][128 * 64];
    __shared__ __align__(16) h16 Bs[2][128 * 64];

    int mt, nt;
    xcd_tiles(mt, nt);
    const int m0 = mt * 128;
    const int n0 = nt * 128;
    const int t = threadIdx.x;
    const int lane = t & 63;
    const int wid = t >> 6;
    const int wr = wid >> 1, wc = wid & 1;

    f32x4 acc[4][4] = {};

    const int rA = wid * 32;
    const int lr = lane >> 3;
    const int sl = lane & 7;

    #define STAGE(b, k0)                                                        \
        _Pragma("unroll")                                                       \
        for (int q = 0; q < 4; q++) {                                           \
            int rb = rA + q * 8;                                                \
            int r  = rb + lr;                                                   \
            int col = (sl ^ (r & 7)) << 3;                                      \
            gload16(Xh + (size_t)(m0 + r) * K + (k0) + col, &As[b][rb * 64]);   \
            gload16(Wt + (size_t)(n0 + r) * K + (k0) + col, &Bs[b][rb * 64]);   \
        }

    STAGE(0, 0)
    __syncthreads();

    const int nkb = K >> 6;
    int buf = 0;
    for (int kb = 0; kb < nkb; kb++) {
        if (kb + 1 < nkb) { STAGE(buf ^ 1, (kb + 1) << 6) }
        #pragma unroll
        for (int ks = 0; ks < 2; ks++) {
            h16x8 af[4], bf[4];
            #pragma unroll
            for (int i = 0; i < 4; i++) {
                int r  = wr * 64 + i * 16 + (lane & 15);
                int s2 = ks * 4 + (lane >> 4);
                af[i] = *(const h16x8*)(&As[buf][r * 64 + ((s2 ^ (r & 7)) << 3)]);
                int c  = wc * 64 + i * 16 + (lane & 15);
                bf[i] = *(const h16x8*)(&Bs[buf][c * 64 + ((s2 ^ (c & 7)) << 3)]);
            }
            #pragma unroll
            for (int i = 0; i < 4; i++)
                #pragma unroll
                for (int j = 0; j < 4; j++)
                    acc[i][j] = __builtin_amdgcn_mfma_f32_16x16x32_f16(af[i], bf[j], acc[i][j], 0, 0, 0);
        }
        __syncthreads();
        buf ^= 1;
    }
    #undef STAGE

    const int crow = (lane >> 4) * 4;
    const int ccol = lane & 15;
    #pragma unroll
    for (int i = 0; i < 4; i++) {
        int rg = m0 + wr * 64 + i * 16 + crow;
        #pragma unroll
        for (int j = 0; j < 4; j++) {
            int cg = n0 + wc * 64 + j * 16 + ccol;
            float b = (cg < nsplit) ? bias_lo[cg] : bias_hi[cg - nsplit];
            h16* dst = (cg < nsplit) ? (Yl + (size_t)cg) : (Yr + (size_t)(cg - nsplit));
            #pragma unroll
            for (int rr = 0; rr < 4; rr++)
                dst[(size_t)(rg + rr) * nsplit] = (h16)(acc[i][j][rr] + b);
        }
    }
}

// ---------- fused per-node GATv2 attention, D=512 (r14 proven version) ----------
// wave per node, 8-edge unroll; raw h16x8 staging (32 VGPR), lazy cvt.
// r11 lesson: no min-wave cap. r15 lesson: 16-slot batch needs >100 VGPR -> spill.
template<int H, int C>
__global__ __launch_bounds__(256) void node_attn(
    const h16* __restrict__ xl, const h16* __restrict__ xr,
    const float* __restrict__ att, const float* __restrict__ bias,
    const int* __restrict__ deg, const int* __restrict__ ssrc,
    h16* __restrict__ out, int Nn)
{
    constexpr int D   = H * C;
    constexpr int EPL = D / 64;     // 8
    constexpr int LPH = C / EPL;    // 16
    int node = blockIdx.x * (blockDim.x >> 6) + (threadIdx.x >> 6);
    if (node >= Nn) return;
    const int lane = threadIdx.x & 63;
    const int base = lane * EPL;

    float xrv[EPL], attv[EPL];
    {
        h16x8 v = *(const h16x8*)(xr + (size_t)node * D + base);
        float4 a0 = *(const float4*)(att + base);
        float4 a1 = *(const float4*)(att + base + 4);
        #pragma unroll
        for (int j = 0; j < 8; j++) xrv[j] = (float)v[j];
        attv[0] = a0.x; attv[1] = a0.y; attv[2] = a0.z; attv[3] = a0.w;
        attv[4] = a1.x; attv[5] = a1.y; attv[6] = a1.z; attv[7] = a1.w;
    }

    float m = -INFINITY, denom = 0.f;
    float agg[EPL] = {};

    auto score8 = [&](h16x8 v) {
        float s = 0.f;
        #pragma unroll
        for (int j = 0; j < 8; j++) {
            float u = (float)v[j] + xrv[j];
            u = u > 0.f ? u : 0.2f * u;
            s += u * attv[j];
        }
        return s;
    };
    auto update8 = [&](float s, h16x8 v) {
        if (s > m) {
            float scale = __expf(m - s);
            denom *= scale;
            #pragma unroll
            for (int j = 0; j < 8; j++) agg[j] *= scale;
            m = s;
        }
        float p = __expf(s - m);
        denom += p;
        #pragma unroll
        for (int j = 0; j < 8; j++) agg[j] += p * (float)v[j];
    };

    const int e0 = node * ELLW, e1 = e0 + deg[node];
    int e = e0;
    for (; e + 7 < e1; e += 8) {           // 8 independent gathers in flight (raw h16x8)
        int s[8];
        h16x8 xv[8];
        float sc[8];
        #pragma unroll
        for (int g = 0; g < 8; g++) s[g] = ssrc[e + g];
        #pragma unroll
        for (int g = 0; g < 8; g++) xv[g] = *(const h16x8*)(xl + (size_t)s[g] * D + base);
        #pragma unroll
        for (int g = 0; g < 8; g++) sc[g] = score8(xv[g]);
        #pragma unroll
        for (int o = 1; o < LPH; o <<= 1)
            #pragma unroll
            for (int g = 0; g < 8; g++) sc[g] += __shfl_xor(sc[g], o, 64);
        #pragma unroll
        for (int g = 0; g < 8; g++) update8(sc[g], xv[g]);
    }
    for (; e + 3 < e1; e += 4) {
        int s[4];
        h16x8 xv[4];
        float sc[4];
        #pragma unroll
        for (int g = 0; g < 4; g++) s[g] = ssrc[e + g];
        #pragma unroll
        for (int g = 0; g < 4; g++) xv[g] = *(const h16x8*)(xl + (size_t)s[g] * D + base);
        #pragma unroll
        for (int g = 0; g < 4; g++) sc[g] = score8(xv[g]);
        #pragma unroll
        for (int o = 1; o < LPH; o <<= 1)
            #pragma unroll
            for (int g = 0; g < 4; g++) sc[g] += __shfl_xor(sc[g], o, 64);
        #pragma unroll
        for (int g = 0; g < 4; g++) update8(sc[g], xv[g]);
    }
    for (; e < e1; e++) {
        int s0 = ssrc[e];
        h16x8 xa = *(const h16x8*)(xl + (size_t)s0 * D + base);
        float sc0 = score8(xa);
        #pragma unroll
        for (int o = 1; o < LPH; o <<= 1) sc0 += __shfl_xor(sc0, o, 64);
        update8(sc0, xa);
    }

    h16* po = out + (size_t)node * D + base;
    h16x8 o8;
    #pragma unroll
    for (int j = 0; j < 8; j++) {
        float v = agg[j] / denom + bias[base + j];
        o8[j] = (h16)(v > 0.f ? v : 0.01f * v);
    }
    *(h16x8*)po = o8;
}

// ---------- layer-3 attention, H=1 D=128: 16 lanes/edge, 4 edge-streams/wave ----------
// outputs h16 (halves pool traffic). r14 proven version.
__global__ __launch_bounds__(256) void node_attn_h1(
    const h16* __restrict__ xl, const h16* __restrict__ xr,
    const float* __restrict__ att, const float* __restrict__ bias,
    const int* __restrict__ deg, const int* __restrict__ ssrc,
    h16* __restrict__ out, int Nn)
{
    int node = blockIdx.x * 4 + (threadIdx.x >> 6);
    if (node >= Nn) return;
    const int lane = threadIdx.x & 63;
    const int q    = lane >> 4;
    const int sl   = lane & 15;
    const int base = sl * 8;

    float xrv[8], attv[8];
    {
        h16x8 v = *(const h16x8*)(xr + (size_t)node * 128 + base);
        float4 a0 = *(const float4*)(att + base);
        float4 a1 = *(const float4*)(att + base + 4);
        #pragma unroll
        for (int j = 0; j < 8; j++) xrv[j] = (float)v[j];
        attv[0] = a0.x; attv[1] = a0.y; attv[2] = a0.z; attv[3] = a0.w;
        attv[4] = a1.x; attv[5] = a1.y; attv[6] = a1.z; attv[7] = a1.w;
    }

    float m = -1e30f, denom = 0.f;
    float agg[8] = {};

    const int e0 = node * ELLW, e1 = e0 + deg[node];
    for (int e = e0 + q; e < e1; e += 4) {
        int src = ssrc[e];
        h16x8 v = *(const h16x8*)(xl + (size_t)src * 128 + base);
        float s = 0.f;
        #pragma unroll
        for (int j = 0; j < 8; j++) {
            float u = (float)v[j] + xrv[j];
            u = u > 0.f ? u : 0.2f * u;
            s += u * attv[j];
        }
        #pragma unroll
        for (int o = 1; o < 16; o <<= 1) s += __shfl_xor(s, o, 64);
        if (s > m) {
            float sc = __expf(m - s);
            denom *= sc;
            #pragma unroll
            for (int j = 0; j < 8; j++) agg[j] *= sc;
            m = s;
        }
        float p = __expf(s - m);
        denom += p;
        #pragma unroll
        for (int j = 0; j < 8; j++) agg[j] += p * (float)v[j];
    }

    #pragma unroll
    for (int o = 16; o <= 32; o <<= 1) {
        float m2 = __shfl_xor(m, o, 64);
        float d2 = __shfl_xor(denom, o, 64);
        float a2[8];
        #pragma unroll
        for (int j = 0; j < 8; j++) a2[j] = __shfl_xor(agg[j], o, 64);
        float mn = fmaxf(m, m2);
        float sa = __expf(m - mn), sb = __expf(m2 - mn);
        denom = denom * sa + d2 * sb;
        #pragma unroll
        for (int j = 0; j < 8; j++) agg[j] = agg[j] * sa + a2[j] * sb;
        m = mn;
    }

    if (lane < 16) {
        h16* po = out + (size_t)node * 128 + base;
        h16x8 o8;
        #pragma unroll
        for (int j = 0; j < 8; j++) {
            float v = agg[j] / denom + bias[base + j];
            o8[j] = (h16)(v > 0.f ? v : 0.01f * v);
        }
        *(h16x8*)po = o8;
    }
}

// ---------- pooling: 256 blocks, slab-parallel, flush on graph change ----------
__global__ __launch_bounds__(128) void pool_partial(
    const h16* __restrict__ h, const int* __restrict__ batch,
    float* __restrict__ pooled, int Nn, int spb)
{
    int t = threadIdx.x;
    int n0 = blockIdx.x * spb;
    int n1 = min(n0 + spb, Nn);
    if (n0 >= n1) return;
    int cur = batch[n0];
    float acc = 0.f;
    for (int n = n0; n < n1; n++) {
        int g = batch[n];
        if (g != cur) {
            atomicAdd(&pooled[cur * 128 + t], acc);
            acc = 0.f; cur = g;
        }
        acc += (float)h[(size_t)n * 128 + t];
    }
    atomicAdd(&pooled[cur * 128 + t], acc);
}

// ---------- classifier ----------
__global__ __launch_bounds__(128) void classifier(
    const float* __restrict__ pooled, const int* __restrict__ start,
    const float* __restrict__ gf,
    const float* __restrict__ W1, const float* __restrict__ b1,
    const float* __restrict__ W2, const float* __restrict__ b2,
    float* __restrict__ out)
{
    __shared__ float z[130];
    __shared__ float hid[128];
    int g = blockIdx.x, t = threadIdx.x;
    float cnt = fmaxf((float)(start[g + 1] - start[g]), 1.f);
    z[t] = pooled[g * 128 + t] / cnt;
    if (t < 2) z[128 + t] = gf[g * 2 + t];
    __syncthreads();
    float s = b1[t];
    for (int k = 0; k < 130; k++) s += z[k] * W1[k * 128 + t];
    hid[t] = s > 0.f ? s : 0.01f * s;
    __syncthreads();
    if (t < 2) {
        float o = b2[t];
        for (int j = 0; j < 128; j++) o += hid[j] * W2[j * 2 + t];
        out[g * 2 + t] = o;
    }
}

// ---------- host ----------
static inline int cdiv(int a, int b) { return (a + b - 1) / b; }

extern "C" void kernel_launch(void* const* d_in, const int* in_sizes, int n_in,
                              void* d_out, int out_size, void* d_ws, size_t ws_size,
                              hipStream_t stream)
{
    const float* x     = (const float*)d_in[0];
    const int*   ei    = (const int*)d_in[1];
    const int*   batch = (const int*)d_in[2];
    const float* gf    = (const float*)d_in[3];

    const float* c_Wl[3]   = {(const float*)d_in[4],  (const float*)d_in[10], (const float*)d_in[16]};
    const float* c_bl[3]   = {(const float*)d_in[5],  (const float*)d_in[11], (const float*)d_in[17]};
    const float* c_Wr[3]   = {(const float*)d_in[6],  (const float*)d_in[12], (const float*)d_in[18]};
    const float* c_br[3]   = {(const float*)d_in[7],  (const float*)d_in[13], (const float*)d_in[19]};
    const float* c_att[3]  = {(const float*)d_in[8],  (const float*)d_in[14], (const float*)d_in[20]};
    const float* c_bias[3] = {(const float*)d_in[9],  (const float*)d_in[15], (const float*)d_in[21]};
    const float* W1 = (const float*)d_in[22];
    const float* b1 = (const float*)d_in[23];
    const float* W2 = (const float*)d_in[24];
    const float* b2 = (const float*)d_in[25];
    float* out = (float*)d_out;

    const int Nn   = in_sizes[0] / 256;   // 16384
    const int E    = in_sizes[1] / 2;     // 131072
    const int G    = in_sizes[3] / 2;     // 64
    const int Etot = E + Nn;

    char* w = (char*)d_ws;
    auto carve = [&](size_t bytes) { void* p = w; w += (bytes + 255) & ~(size_t)255; return p; };
    h16*   ylb  = (h16*)carve((size_t)Nn * 512 * 2);    // xl buffer
    h16*   yrb  = (h16*)carve((size_t)Nn * 512 * 2);    // xr buffer
    h16*   xh   = (h16*)carve((size_t)Nn * 512 * 2);    // f16 activations
    h16*   b0   = (h16*)carve((size_t)Nn * 128 * 2);    // layer-3 output (f16)
    h16* wt1 = (h16*)carve((size_t)1024 * 256 * 2);     // [Wl1^T ; Wr1^T]
    h16* wt2 = (h16*)carve((size_t)1024 * 512 * 2);     // [Wl2^T ; Wr2^T]
    h16* wt3 = (h16*)carve((size_t)256 * 512 * 2);      // [Wl3^T ; Wr3^T]
    int* cursor = (int*)carve((size_t)Nn * 4);          // becomes deg after scatter
    int* ssrc   = (int*)carve((size_t)Nn * ELLW * 4);   // ELL adjacency
    int* start  = (int*)carve((size_t)(G + 1) * 4);
    float* pooled = (float*)carve((size_t)G * 128 * 4);
    (void)ws_size; (void)n_in; (void)out_size;

    // ---- mega-prep: weight transpose (896 blocks) + flat work ----
    {
        const int flat = Nn * 32 + Nn + G * 128 + Nn;
        prep<<<896 + cdiv(flat, 256), 256, 0, stream>>>(
            c_Wl[0], c_Wr[0], c_Wl[1], c_Wr[1], c_Wl[2], c_Wr[2],
            wt1, wt1 + 512 * 256, wt2, wt2 + 512 * 512, wt3, wt3 + 128 * 512,
            x, xh, cursor, batch, start, pooled, Nn, G);
    }
    // ---- ELL adjacency (dst-grouped) ----
    scatter_ell<<<cdiv(Etot, 256), 256, 0, stream>>>(ei, E, Nn, cursor, ssrc);

    const int node_blocks = cdiv(Nn, 4);

    // ---- layer 1: xh [N,256] -> xl|xr [N,512] each ----
    gemm_f16_wide<<<dim3(1024 / 256, Nn / 128), 512, 0, stream>>>(xh, wt1, c_bl[0], c_br[0], 512, ylb, yrb, Nn, 1024, 256);
    node_attn<4, 128><<<node_blocks, 256, 0, stream>>>(ylb, yrb, c_att[0], c_bias[0], cursor, ssrc, xh, Nn);
    // ---- layer 2 ----
    gemm_f16_wide<<<dim3(1024 / 256, Nn / 128), 512, 0, stream>>>(xh, wt2, c_bl[1], c_br[1], 512, ylb, yrb, Nn, 1024, 512);
    node_attn<4, 128><<<node_blocks, 256, 0, stream>>>(ylb, yrb, c_att[1], c_bias[1], cursor, ssrc, xh, Nn);
    // ---- layer 3: xh [N,512] -> xl|xr [N,128] each (H=1) ----
    gemm_f16_mfma<<<dim3(256 / 128, Nn / 128), 256, 0, stream>>>(xh, wt3, c_bl[2], c_br[2], 128, ylb, yrb, Nn, 256, 512);
    node_attn_h1<<<node_blocks, 256, 0, stream>>>(ylb, yrb, c_att[2], c_bias[2], cursor, ssrc, b0, Nn);

    // ---- global mean pool (slab-parallel) + classifier ----
    {
        const int nblk = 256;
        const int spb  = cdiv(Nn, nblk);
        pool_partial<<<nblk, 128, 0, stream>>>(b0, batch, pooled, Nn, spb);
    }
    classifier<<<G, 128, 0, stream>>>(pooled, start, gf, W1, b1, W2, b2, out);
}